// Round 5
// baseline (890.542 us; speedup 1.0000x reference)
//
#include <hip/hip_runtime.h>

#define S_   2048
#define DM_  1024
#define NH_  16
#define HD_  64
#define KDIM 1024
#define QB_  128
#define NWORDS (2u*S_*NH_*S_/64u)   // 2,097,152 packed u64 words

typedef __attribute__((ext_vector_type(8))) short  shortx8;
typedef __attribute__((ext_vector_type(4))) float  floatx4;

#define AS1 __attribute__((address_space(1)))
#define AS3 __attribute__((address_space(3)))

__device__ __forceinline__ unsigned short f2bf(float f) {
  unsigned u = __float_as_uint(f);
  u += 0x7FFFu + ((u >> 16) & 1u);
  return (unsigned short)(u >> 16);
}

__device__ __forceinline__ void gld_lds16(const void* g, unsigned short* l) {
  __builtin_amdgcn_global_load_lds((const AS1 void*)g, (AS3 void*)l, 16, 0, 0);
}

// ---------------- fused QKV GEMM + mask bit-pack (one dispatch, overlapped) ----------------
// blockIdx.y < 8  : mask pack blocks (256 of them, dispatched first -> co-resident with gemm)
// blockIdx.y >= 8 : gemm blocks (bn = y-8), m97 structure.
__global__ __launch_bounds__(256) void qkv_gemm_pack(const void* __restrict__ Xv,
                                                     const void* __restrict__ Wv,
                                                     const void* __restrict__ maskp,
                                                     unsigned short* __restrict__ Qg,
                                                     unsigned short* __restrict__ Kg,
                                                     unsigned short* __restrict__ Vt,
                                                     unsigned long long* __restrict__ pk)
{
  const int tid  = threadIdx.x;
  const int wid  = tid >> 6,  lane = tid & 63;

  if (blockIdx.y < 8) {
    // ---- mask pack: detect elem size, then ballot-pack 64 elems -> 1 u64 ----
    __shared__ int psd[3];
    if (tid < 3) psd[tid] = 1;
    __syncthreads();
    {
      unsigned mv = ((const unsigned*)maskp)[tid];
      bool w4 = (mv <= 1u) || (mv == 0x3F800000u);             // i32 or f32 {0,1}
      unsigned lo = mv & 0xFFFFu, hi = mv >> 16;
      bool w2 = ((lo==0u)||(lo==0x3F80u)) && ((hi==0u)||(hi==0x3F80u));
      unsigned long long B4 = __ballot(w4), B2 = __ballot(w2);
      if (lane == 0) {
        if (~B4) atomicAnd(&psd[0], 0);
        if (~B2) atomicAnd(&psd[1], 0);
      }
    }
    __syncthreads();
    const int esz = psd[0] ? 4 : (psd[1] ? 2 : 1);

    const int pid = blockIdx.y * 32 + blockIdx.x;      // 0..255
    const unsigned gw = (unsigned)(pid*4 + wid);       // 0..1023
    unsigned wbase = gw * (NWORDS/1024u);              // 2048 words/wave
    for (int rnd = 0; rnd < (int)(NWORDS/1024u/16u); ++rnd) {
      unsigned w0 = wbase + rnd*16;
      unsigned long long B[16];
      if (esz == 4) {
        const unsigned* mp = (const unsigned*)maskp;
        unsigned v[16];
        #pragma unroll
        for (int j = 0; j < 16; ++j) v[j] = mp[(size_t)(w0+j)*64 + lane];
        #pragma unroll
        for (int j = 0; j < 16; ++j) B[j] = __ballot(v[j] != 0u);
      } else if (esz == 2) {
        const unsigned short* mp = (const unsigned short*)maskp;
        unsigned short v[16];
        #pragma unroll
        for (int j = 0; j < 16; ++j) v[j] = mp[(size_t)(w0+j)*64 + lane];
        #pragma unroll
        for (int j = 0; j < 16; ++j) B[j] = __ballot(v[j] != 0);
      } else {
        const unsigned char* mp = (const unsigned char*)maskp;
        unsigned char v[16];
        #pragma unroll
        for (int j = 0; j < 16; ++j) v[j] = mp[(size_t)(w0+j)*64 + lane];
        #pragma unroll
        for (int j = 0; j < 16; ++j) B[j] = __ballot(v[j] != 0);
      }
      if (lane == 0) {
        #pragma unroll
        for (int j = 0; j < 16; ++j) pk[w0 + j] = B[j];
      }
    }
    return;
  }

  // ---- gemm blocks ----
  __shared__ unsigned short lA[128*64];
  __shared__ unsigned short lB[128*64];
  __shared__ int sx;
  const int quad = lane >> 4, l16  = lane & 15;
  const int bm = blockIdx.x, bn = blockIdx.y - 8;
  const int wM = (wid >> 1) * 64, wN = (wid & 1) * 64;

  if (tid == 0) sx = 0;
  __syncthreads();
  {
    unsigned xv = ((const unsigned*)Xv)[tid];
    unsigned b1 = (xv >> 8) & 0x7Fu;
    bool pb = (b1 >= 0x32u && b1 <= 0x41u);
    unsigned long long bal = __ballot(pb);
    if (lane == 0) atomicAdd(&sx, (int)__popcll(bal));
  }
  __syncthreads();
  const int xbf = sx > 128;

  floatx4 acc[4][4] = {};

  for (int kt = 0; kt < KDIM; kt += 64) {
    __syncthreads();
    if (xbf) {
      const unsigned short* X = (const unsigned short*)Xv;
      const unsigned short* W = (const unsigned short*)Wv;
      #pragma unroll
      for (int p = 0; p < 4; ++p) {
        int chunk = p*256 + tid;
        int r = chunk >> 3, c = chunk & 7;
        gld_lds16(X + (size_t)(bm*128 + r)*KDIM + kt + c*8, lA + chunk*8);
      }
      #pragma unroll
      for (int p = 0; p < 4; ++p) {
        int chunk = p*256 + tid;
        int r = chunk >> 3, c = chunk & 7;
        gld_lds16(W + (size_t)(bn*128 + r)*KDIM + kt + c*8, lB + chunk*8);
      }
    } else {
      const float* X = (const float*)Xv;
      const float* W = (const float*)Wv;
      #pragma unroll
      for (int p = 0; p < 8; ++p) {
        int c4 = p*256 + tid;
        int r = c4 >> 4, c = c4 & 15;
        float4 v = *(const float4*)(X + (size_t)(bm*128 + r)*KDIM + kt + c*4);
        unsigned short* d = lA + r*64 + c*4;
        d[0]=f2bf(v.x); d[1]=f2bf(v.y); d[2]=f2bf(v.z); d[3]=f2bf(v.w);
      }
      #pragma unroll
      for (int p = 0; p < 8; ++p) {
        int c4 = p*256 + tid;
        int r = c4 >> 4, c = c4 & 15;
        float4 v = *(const float4*)(W + (size_t)(bn*128 + r)*KDIM + kt + c*4);
        unsigned short* d = lB + r*64 + c*4;
        d[0]=f2bf(v.x); d[1]=f2bf(v.y); d[2]=f2bf(v.z); d[3]=f2bf(v.w);
      }
    }
    __syncthreads();

    #pragma unroll
    for (int ks = 0; ks < 2; ++ks) {
      shortx8 af[4], bfr[4];
      #pragma unroll
      for (int mi = 0; mi < 4; ++mi)
        af[mi] = *(const shortx8*)(lA + (wM + mi*16 + l16)*64 + ks*32 + quad*8);
      #pragma unroll
      for (int ni = 0; ni < 4; ++ni)
        bfr[ni] = *(const shortx8*)(lB + (wN + ni*16 + l16)*64 + ks*32 + quad*8);
      #pragma unroll
      for (int mi = 0; mi < 4; ++mi)
        #pragma unroll
        for (int ni = 0; ni < 4; ++ni)
          acc[mi][ni] = __builtin_amdgcn_mfma_f32_16x16x32_bf16(af[mi], bfr[ni], acc[mi][ni], 0, 0, 0);
    }
  }

  if (bn < 8) {
    #pragma unroll
    for (int mi = 0; mi < 4; ++mi)
      #pragma unroll
      for (int ni = 0; ni < 4; ++ni)
        #pragma unroll
        for (int r = 0; r < 4; ++r) {
          int m = bm*128 + wM + mi*16 + quad*4 + r;
          int n = bn*128 + wN + ni*16 + l16;
          int b = m >> 11, q = m & 2047, h = n >> 6, d = n & 63;
          Qg[(((size_t)(b*NH_ + h))*S_ + q)*HD_ + d] = f2bf(acc[mi][ni][r] * 0.125f);
        }
  } else if (bn < 16) {
    #pragma unroll
    for (int mi = 0; mi < 4; ++mi)
      #pragma unroll
      for (int ni = 0; ni < 4; ++ni)
        #pragma unroll
        for (int r = 0; r < 4; ++r) {
          int m = bm*128 + wM + mi*16 + quad*4 + r;
          int n = bn*128 + wN + ni*16 + l16 - 1024;
          int b = m >> 11, t = m & 2047, h = n >> 6, d = n & 63;
          Kg[(((size_t)(b*NH_ + h))*S_ + t)*HD_ + d] = f2bf(acc[mi][ni][r]);
        }
  } else {
    #pragma unroll
    for (int mi = 0; mi < 4; ++mi)
      #pragma unroll
      for (int ni = 0; ni < 4; ++ni) {
        int m0 = bm*128 + wM + mi*16 + quad*4;
        int n  = bn*128 + wN + ni*16 + l16 - 2048;
        int b = m0 >> 11, t = m0 & 2047, h = n >> 6, d = n & 63;
        ushort4 u;
        u.x = f2bf(acc[mi][ni][0]); u.y = f2bf(acc[mi][ni][1]);
        u.z = f2bf(acc[mi][ni][2]); u.w = f2bf(acc[mi][ni][3]);
        *(ushort4*)(Vt + (((size_t)(b*NH_ + h))*HD_ + d)*S_ + t) = u;
      }
  }
}

// ---------------- fused masked flash attention: packed mask, shared K/V frags ----------------
__global__ __launch_bounds__(256, 2) void attn_kernel(const unsigned short* __restrict__ Qg,
                                                      const unsigned short* __restrict__ Kg,
                                                      const unsigned short* __restrict__ Vt,
                                                      const unsigned long long* __restrict__ pk,
                                                      const void* __restrict__ xg,
                                                      void* __restrict__ outv)
{
  __shared__ unsigned short lQ[QB_*HD_];     // 16 KB; reused as per-wave P after qf extraction
  __shared__ unsigned short lK[2][64*HD_];   // 16 KB dbuf
  __shared__ unsigned short lVt[2][HD_*64];  // 16 KB dbuf
  __shared__ int sdet;

  const int tid  = threadIdx.x;
  const int wid  = tid >> 6,  lane = tid & 63;
  const int quad = lane >> 4, l16  = lane & 15;
  const int qb = blockIdx.x * QB_;
  const int h  = blockIdx.y, b = blockIdx.z;
  const int bh = b*NH_ + h;

  if (tid == 0) sdet = 0;
  __syncthreads();
  {
    unsigned xv = ((const unsigned*)xg)[tid];
    unsigned b1 = (xv >> 8) & 0x7Fu;
    bool pb = (b1 >= 0x32u && b1 <= 0x41u);
    unsigned long long BX = __ballot(pb);
    if (lane == 0) atomicAdd(&sdet, (int)__popcll(BX));
  }

  #pragma unroll
  for (int p = 0; p < 4; ++p) {
    int chunk = p*256 + tid;
    gld_lds16(Qg + ((size_t)bh*S_ + qb)*HD_ + chunk*8, lQ + chunk*8);
  }

  auto stage = [&](int t0, int buf) {
    #pragma unroll
    for (int p = 0; p < 2; ++p) {
      int chunk = p*256 + tid;
      gld_lds16(Kg + ((size_t)bh*S_ + t0)*HD_ + chunk*8, lK[buf] + chunk*8);
    }
    #pragma unroll
    for (int p = 0; p < 2; ++p) {
      int chunk = p*256 + tid;
      int r = chunk >> 3, c = chunk & 7;
      gld_lds16(Vt + ((size_t)bh*HD_ + r)*S_ + t0 + c*8, lVt[buf] + chunk*8);
    }
  };

  // packed-mask word base for this lane's 8 rows: row (qh,r) -> q = qb+wid*32+qh*16+quad*4+r
  const size_t mw0 = ((size_t)(b*S_ + qb + wid*32 + quad*4)*NH_ + h)*(S_/64);
  // per-(qh,r) offset: (qh*16 + r) * NH_*(S_/64) = (qh*16+r)*512

  auto loadw = [&](int t0, unsigned long long* w) {
    int wi = t0 >> 6;
    #pragma unroll
    for (int qh = 0; qh < 2; ++qh)
      #pragma unroll
      for (int r = 0; r < 4; ++r)
        w[qh*4+r] = pk[mw0 + (size_t)(qh*16 + r)*512 + wi];
  };

  unsigned long long wc[8], wn[8];
  stage(0, 0);
  loadw(0, wc);
  __syncthreads();
  const int obf = sdet > 128;

  shortx8 qf[2][2];
  #pragma unroll
  for (int qh = 0; qh < 2; ++qh)
    #pragma unroll
    for (int ks = 0; ks < 2; ++ks)
      qf[qh][ks] = *(const shortx8*)(lQ + (wid*32 + qh*16 + l16)*HD_ + ks*32 + quad*8);

  floatx4 acc[2][4] = {};
  float lsum[2][4] = {};
  unsigned short* lPw = lQ + wid*2048;   // this wave's 32x64 P region (its own Q rows, now dead)

  for (int t0 = 0; t0 < S_; t0 += 64) {
    const int cur = (t0 >> 6) & 1;
    const bool more = (t0 + 64 < S_);
    if (more) {
      stage(t0 + 64, cur ^ 1);
      loadw(t0 + 64, wn);
    }

    // S = Q K^T — K fragment shared across both qh halves
    floatx4 sc[2][4] = {};
    #pragma unroll
    for (int tile = 0; tile < 4; ++tile)
      #pragma unroll
      for (int ks = 0; ks < 2; ++ks) {
        shortx8 kf = *(const shortx8*)(lK[cur] + (tile*16 + l16)*64 + ks*32 + quad*8);
        sc[0][tile] = __builtin_amdgcn_mfma_f32_16x16x32_bf16(qf[0][ks], kf, sc[0][tile], 0, 0, 0);
        sc[1][tile] = __builtin_amdgcn_mfma_f32_16x16x32_bf16(qf[1][ks], kf, sc[1][tile], 0, 0, 0);
      }

    // max-free masked softmax; P into per-wave LDS (xor-swizzled)
    #pragma unroll
    for (int qh = 0; qh < 2; ++qh)
      #pragma unroll
      for (int r = 0; r < 4; ++r) {
        unsigned long long w = wc[qh*4+r] >> l16;
        #pragma unroll
        for (int tile = 0; tile < 4; ++tile) {
          float e = __expf(sc[qh][tile][r]);
          e = ((w >> (tile*16)) & 1ull) ? e : 0.f;
          lsum[qh][r] += e;
          int row = qh*16 + quad*4 + r;
          int col = tile*16 + l16;
          lPw[(row << 6) + (((col >> 3) ^ (row & 7)) << 3) + (col & 7)] = f2bf(e);
        }
      }

    // P·V — V fragment shared across both qh halves
    shortx8 pa[2][2];
    #pragma unroll
    for (int qh = 0; qh < 2; ++qh)
      #pragma unroll
      for (int ks = 0; ks < 2; ++ks) {
        int prow = qh*16 + l16;
        pa[qh][ks] = *(const shortx8*)(lPw + (prow << 6) + (((ks*4 + quad) ^ (prow & 7)) << 3));
      }
    #pragma unroll
    for (int ks = 0; ks < 2; ++ks)
      #pragma unroll
      for (int d = 0; d < 4; ++d) {
        shortx8 vb = *(const shortx8*)(lVt[cur] + (d*16 + l16)*64 + ks*32 + quad*8);
        acc[0][d] = __builtin_amdgcn_mfma_f32_16x16x32_bf16(pa[0][ks], vb, acc[0][d], 0, 0, 0);
        acc[1][d] = __builtin_amdgcn_mfma_f32_16x16x32_bf16(pa[1][ks], vb, acc[1][d], 0, 0, 0);
      }

    #pragma unroll
    for (int i = 0; i < 8; ++i) wc[i] = wn[i];
    __syncthreads();   // drains next-tile staging (a full compute phase old)
  }

  float rinv[2][4];
  #pragma unroll
  for (int qh = 0; qh < 2; ++qh)
    #pragma unroll
    for (int r = 0; r < 4; ++r) {
      float l = lsum[qh][r];
      #pragma unroll
      for (int o = 1; o < 16; o <<= 1) l += __shfl_xor(l, o);
      rinv[qh][r] = 1.f / l;
    }

  #pragma unroll
  for (int qh = 0; qh < 2; ++qh)
    #pragma unroll
    for (int d = 0; d < 4; ++d)
      #pragma unroll
      for (int r = 0; r < 4; ++r) {
        int q = qb + wid*32 + qh*16 + quad*4 + r;
        size_t oi = ((size_t)b*S_ + q)*DM_ + h*HD_ + d*16 + l16;
        float v = acc[qh][d][r] * rinv[qh][r];
        if (obf) ((unsigned short*)outv)[oi] = f2bf(v);
        else     ((float*)outv)[oi]          = v;
      }
}

extern "C" void kernel_launch(void* const* d_in, const int* in_sizes, int n_in,
                              void* d_out, int out_size, void* d_ws, size_t ws_size,
                              hipStream_t stream) {
  (void)in_sizes; (void)n_in; (void)out_size; (void)ws_size;
  const void* X    = d_in[0];
  const void* W    = d_in[1];
  const void* mask = d_in[2];
  const size_t SEG = (size_t)2*NH_*S_*HD_*2;  // 8.39 MB per tensor
  unsigned short* Qg = (unsigned short*)((char*)d_ws + 256);
  unsigned short* Kg = (unsigned short*)((char*)d_ws + 256 + SEG);
  unsigned short* Vt = (unsigned short*)((char*)d_ws + 256 + 2*SEG);
  unsigned long long* pk = (unsigned long long*)((char*)d_ws + 256 + 3*SEG);  // 16.8 MB

  qkv_gemm_pack<<<dim3(32, 32), 256, 0, stream>>>(X, W, mask, Qg, Kg, Vt, pk);
  attn_kernel<<<dim3(S_/QB_, NH_, 2), 256, 0, stream>>>(Qg, Kg, Vt, pk, X, d_out);
}

// Round 6
// 886.898 us; speedup vs baseline: 1.0041x; 1.0041x over previous
//
#include <hip/hip_runtime.h>

#define S_   2048
#define DM_  1024
#define NH_  16
#define HD_  64
#define KDIM 1024
#define QB_  128
#define NWORDS (2u*S_*NH_*S_/64u)   // 2,097,152 packed u64 words

typedef __attribute__((ext_vector_type(8))) short  shortx8;
typedef __attribute__((ext_vector_type(4))) float  floatx4;

#define AS1 __attribute__((address_space(1)))
#define AS3 __attribute__((address_space(3)))

__device__ __forceinline__ unsigned short f2bf(float f) {
  unsigned u = __float_as_uint(f);
  u += 0x7FFFu + ((u >> 16) & 1u);
  return (unsigned short)(u >> 16);
}

__device__ __forceinline__ void gld_lds16(const void* g, unsigned short* l) {
  __builtin_amdgcn_global_load_lds((const AS1 void*)g, (AS3 void*)l, 16, 0, 0);
}

// ---------------- fused QKV GEMM + mask bit-pack (one dispatch, overlapped) ----------------
// blockIdx.y < 8  : mask pack blocks (256, dispatched first -> co-resident with gemm).
//                   Mask reads are NON-TEMPORAL so the 537 MB stream doesn't evict the
//                   gemm's X/W L3 working set (suspected R5 regression mechanism).
// blockIdx.y >= 8 : gemm blocks (bn = y-8), m97 structure.
__global__ __launch_bounds__(256) void qkv_gemm_pack(const void* __restrict__ Xv,
                                                     const void* __restrict__ Wv,
                                                     const void* __restrict__ maskp,
                                                     unsigned short* __restrict__ Qg,
                                                     unsigned short* __restrict__ Kg,
                                                     unsigned short* __restrict__ Vt,
                                                     unsigned long long* __restrict__ pk)
{
  const int tid  = threadIdx.x;
  const int wid  = tid >> 6,  lane = tid & 63;

  if (blockIdx.y < 8) {
    __shared__ int psd[3];
    if (tid < 3) psd[tid] = 1;
    __syncthreads();
    {
      unsigned mv = ((const unsigned*)maskp)[tid];
      bool w4 = (mv <= 1u) || (mv == 0x3F800000u);             // i32 or f32 {0,1}
      unsigned lo = mv & 0xFFFFu, hi = mv >> 16;
      bool w2 = ((lo==0u)||(lo==0x3F80u)) && ((hi==0u)||(hi==0x3F80u));
      unsigned long long B4 = __ballot(w4), B2 = __ballot(w2);
      if (lane == 0) {
        if (~B4) atomicAnd(&psd[0], 0);
        if (~B2) atomicAnd(&psd[1], 0);
      }
    }
    __syncthreads();
    const int esz = psd[0] ? 4 : (psd[1] ? 2 : 1);

    const int pid = blockIdx.y * 32 + blockIdx.x;      // 0..255
    const unsigned gw = (unsigned)(pid*4 + wid);       // 0..1023
    unsigned wbase = gw * (NWORDS/1024u);              // 2048 words/wave
    for (int rnd = 0; rnd < (int)(NWORDS/1024u/16u); ++rnd) {
      unsigned w0 = wbase + rnd*16;
      unsigned long long B[16];
      if (esz == 4) {
        const unsigned* mp = (const unsigned*)maskp;
        unsigned v[16];
        #pragma unroll
        for (int j = 0; j < 16; ++j) v[j] = __builtin_nontemporal_load(mp + (size_t)(w0+j)*64 + lane);
        #pragma unroll
        for (int j = 0; j < 16; ++j) B[j] = __ballot(v[j] != 0u);
      } else if (esz == 2) {
        const unsigned short* mp = (const unsigned short*)maskp;
        unsigned short v[16];
        #pragma unroll
        for (int j = 0; j < 16; ++j) v[j] = __builtin_nontemporal_load(mp + (size_t)(w0+j)*64 + lane);
        #pragma unroll
        for (int j = 0; j < 16; ++j) B[j] = __ballot(v[j] != 0);
      } else {
        const unsigned char* mp = (const unsigned char*)maskp;
        unsigned char v[16];
        #pragma unroll
        for (int j = 0; j < 16; ++j) v[j] = __builtin_nontemporal_load(mp + (size_t)(w0+j)*64 + lane);
        #pragma unroll
        for (int j = 0; j < 16; ++j) B[j] = __ballot(v[j] != 0);
      }
      if (lane == 0) {
        #pragma unroll
        for (int j = 0; j < 16; ++j) __builtin_nontemporal_store(B[j], pk + w0 + j);
      }
    }
    return;
  }

  // ---- gemm blocks ----
  __shared__ unsigned short lA[128*64];
  __shared__ unsigned short lB[128*64];
  __shared__ int sx;
  const int quad = lane >> 4, l16  = lane & 15;
  const int bm = blockIdx.x, bn = blockIdx.y - 8;
  const int wM = (wid >> 1) * 64, wN = (wid & 1) * 64;

  if (tid == 0) sx = 0;
  __syncthreads();
  {
    unsigned xv = ((const unsigned*)Xv)[tid];
    unsigned b1 = (xv >> 8) & 0x7Fu;
    bool pb = (b1 >= 0x32u && b1 <= 0x41u);
    unsigned long long bal = __ballot(pb);
    if (lane == 0) atomicAdd(&sx, (int)__popcll(bal));
  }
  __syncthreads();
  const int xbf = sx > 128;

  floatx4 acc[4][4] = {};

  for (int kt = 0; kt < KDIM; kt += 64) {
    __syncthreads();
    if (xbf) {
      const unsigned short* X = (const unsigned short*)Xv;
      const unsigned short* W = (const unsigned short*)Wv;
      #pragma unroll
      for (int p = 0; p < 4; ++p) {
        int chunk = p*256 + tid;
        int r = chunk >> 3, c = chunk & 7;
        gld_lds16(X + (size_t)(bm*128 + r)*KDIM + kt + c*8, lA + chunk*8);
      }
      #pragma unroll
      for (int p = 0; p < 4; ++p) {
        int chunk = p*256 + tid;
        int r = chunk >> 3, c = chunk & 7;
        gld_lds16(W + (size_t)(bn*128 + r)*KDIM + kt + c*8, lB + chunk*8);
      }
    } else {
      const float* X = (const float*)Xv;
      const float* W = (const float*)Wv;
      #pragma unroll
      for (int p = 0; p < 8; ++p) {
        int c4 = p*256 + tid;
        int r = c4 >> 4, c = c4 & 15;
        float4 v = *(const float4*)(X + (size_t)(bm*128 + r)*KDIM + kt + c*4);
        unsigned short* d = lA + r*64 + c*4;
        d[0]=f2bf(v.x); d[1]=f2bf(v.y); d[2]=f2bf(v.z); d[3]=f2bf(v.w);
      }
      #pragma unroll
      for (int p = 0; p < 8; ++p) {
        int c4 = p*256 + tid;
        int r = c4 >> 4, c = c4 & 15;
        float4 v = *(const float4*)(W + (size_t)(bn*128 + r)*KDIM + kt + c*4);
        unsigned short* d = lB + r*64 + c*4;
        d[0]=f2bf(v.x); d[1]=f2bf(v.y); d[2]=f2bf(v.z); d[3]=f2bf(v.w);
      }
    }
    __syncthreads();

    #pragma unroll
    for (int ks = 0; ks < 2; ++ks) {
      shortx8 af[4], bfr[4];
      #pragma unroll
      for (int mi = 0; mi < 4; ++mi)
        af[mi] = *(const shortx8*)(lA + (wM + mi*16 + l16)*64 + ks*32 + quad*8);
      #pragma unroll
      for (int ni = 0; ni < 4; ++ni)
        bfr[ni] = *(const shortx8*)(lB + (wN + ni*16 + l16)*64 + ks*32 + quad*8);
      #pragma unroll
      for (int mi = 0; mi < 4; ++mi)
        #pragma unroll
        for (int ni = 0; ni < 4; ++ni)
          acc[mi][ni] = __builtin_amdgcn_mfma_f32_16x16x32_bf16(af[mi], bfr[ni], acc[mi][ni], 0, 0, 0);
    }
  }

  if (bn < 8) {
    #pragma unroll
    for (int mi = 0; mi < 4; ++mi)
      #pragma unroll
      for (int ni = 0; ni < 4; ++ni)
        #pragma unroll
        for (int r = 0; r < 4; ++r) {
          int m = bm*128 + wM + mi*16 + quad*4 + r;
          int n = bn*128 + wN + ni*16 + l16;
          int b = m >> 11, q = m & 2047, h = n >> 6, d = n & 63;
          Qg[(((size_t)(b*NH_ + h))*S_ + q)*HD_ + d] = f2bf(acc[mi][ni][r] * 0.125f);
        }
  } else if (bn < 16) {
    #pragma unroll
    for (int mi = 0; mi < 4; ++mi)
      #pragma unroll
      for (int ni = 0; ni < 4; ++ni)
        #pragma unroll
        for (int r = 0; r < 4; ++r) {
          int m = bm*128 + wM + mi*16 + quad*4 + r;
          int n = bn*128 + wN + ni*16 + l16 - 1024;
          int b = m >> 11, t = m & 2047, h = n >> 6, d = n & 63;
          Kg[(((size_t)(b*NH_ + h))*S_ + t)*HD_ + d] = f2bf(acc[mi][ni][r]);
        }
  } else {
    #pragma unroll
    for (int mi = 0; mi < 4; ++mi)
      #pragma unroll
      for (int ni = 0; ni < 4; ++ni) {
        int m0 = bm*128 + wM + mi*16 + quad*4;
        int n  = bn*128 + wN + ni*16 + l16 - 2048;
        int b = m0 >> 11, t = m0 & 2047, h = n >> 6, d = n & 63;
        ushort4 u;
        u.x = f2bf(acc[mi][ni][0]); u.y = f2bf(acc[mi][ni][1]);
        u.z = f2bf(acc[mi][ni][2]); u.w = f2bf(acc[mi][ni][3]);
        *(ushort4*)(Vt + (((size_t)(b*NH_ + h))*HD_ + d)*S_ + t) = u;
      }
  }
}

// ---------------- fused masked flash attention: packed mask, shared K/V frags ----------------
__global__ __launch_bounds__(256, 2) void attn_kernel(const unsigned short* __restrict__ Qg,
                                                      const unsigned short* __restrict__ Kg,
                                                      const unsigned short* __restrict__ Vt,
                                                      const unsigned long long* __restrict__ pk,
                                                      const void* __restrict__ xg,
                                                      void* __restrict__ outv)
{
  __shared__ unsigned short lQ[QB_*HD_];     // 16 KB; reused as per-wave P after qf extraction
  __shared__ unsigned short lK[2][64*HD_];   // 16 KB dbuf
  __shared__ unsigned short lVt[2][HD_*64];  // 16 KB dbuf
  __shared__ int sdet;

  const int tid  = threadIdx.x;
  const int wid  = tid >> 6,  lane = tid & 63;
  const int quad = lane >> 4, l16  = lane & 15;
  const int qb = blockIdx.x * QB_;
  const int h  = blockIdx.y, b = blockIdx.z;
  const int bh = b*NH_ + h;

  if (tid == 0) sdet = 0;
  __syncthreads();
  {
    unsigned xv = ((const unsigned*)xg)[tid];
    unsigned b1 = (xv >> 8) & 0x7Fu;
    bool pb = (b1 >= 0x32u && b1 <= 0x41u);
    unsigned long long BX = __ballot(pb);
    if (lane == 0) atomicAdd(&sdet, (int)__popcll(BX));
  }

  #pragma unroll
  for (int p = 0; p < 4; ++p) {
    int chunk = p*256 + tid;
    gld_lds16(Qg + ((size_t)bh*S_ + qb)*HD_ + chunk*8, lQ + chunk*8);
  }

  auto stage = [&](int t0, int buf) {
    #pragma unroll
    for (int p = 0; p < 2; ++p) {
      int chunk = p*256 + tid;
      gld_lds16(Kg + ((size_t)bh*S_ + t0)*HD_ + chunk*8, lK[buf] + chunk*8);
    }
    #pragma unroll
    for (int p = 0; p < 2; ++p) {
      int chunk = p*256 + tid;
      int r = chunk >> 3, c = chunk & 7;
      gld_lds16(Vt + ((size_t)bh*HD_ + r)*S_ + t0 + c*8, lVt[buf] + chunk*8);
    }
  };

  const size_t mw0 = ((size_t)(b*S_ + qb + wid*32 + quad*4)*NH_ + h)*(S_/64);

  auto loadw = [&](int t0, unsigned long long* w) {
    int wi = t0 >> 6;
    #pragma unroll
    for (int qh = 0; qh < 2; ++qh)
      #pragma unroll
      for (int r = 0; r < 4; ++r)
        w[qh*4+r] = pk[mw0 + (size_t)(qh*16 + r)*512 + wi];
  };

  unsigned long long wc[8], wn[8];
  stage(0, 0);
  loadw(0, wc);
  __syncthreads();
  const int obf = sdet > 128;

  shortx8 qf[2][2];
  #pragma unroll
  for (int qh = 0; qh < 2; ++qh)
    #pragma unroll
    for (int ks = 0; ks < 2; ++ks)
      qf[qh][ks] = *(const shortx8*)(lQ + (wid*32 + qh*16 + l16)*HD_ + ks*32 + quad*8);

  floatx4 acc[2][4] = {};
  float lsum[2][4] = {};
  unsigned short* lPw = lQ + wid*2048;   // this wave's 32x64 P region (its own Q rows, now dead)

  for (int t0 = 0; t0 < S_; t0 += 64) {
    const int cur = (t0 >> 6) & 1;
    const bool more = (t0 + 64 < S_);
    if (more) {
      stage(t0 + 64, cur ^ 1);
      loadw(t0 + 64, wn);
    }

    // S = Q K^T — K fragment shared across both qh halves
    floatx4 sc[2][4] = {};
    #pragma unroll
    for (int tile = 0; tile < 4; ++tile)
      #pragma unroll
      for (int ks = 0; ks < 2; ++ks) {
        shortx8 kf = *(const shortx8*)(lK[cur] + (tile*16 + l16)*64 + ks*32 + quad*8);
        sc[0][tile] = __builtin_amdgcn_mfma_f32_16x16x32_bf16(qf[0][ks], kf, sc[0][tile], 0, 0, 0);
        sc[1][tile] = __builtin_amdgcn_mfma_f32_16x16x32_bf16(qf[1][ks], kf, sc[1][tile], 0, 0, 0);
      }

    // max-free masked softmax; P into per-wave LDS (xor-swizzled)
    #pragma unroll
    for (int qh = 0; qh < 2; ++qh)
      #pragma unroll
      for (int r = 0; r < 4; ++r) {
        unsigned long long w = wc[qh*4+r] >> l16;
        #pragma unroll
        for (int tile = 0; tile < 4; ++tile) {
          float e = __expf(sc[qh][tile][r]);
          e = ((w >> (tile*16)) & 1ull) ? e : 0.f;
          lsum[qh][r] += e;
          int row = qh*16 + quad*4 + r;
          int col = tile*16 + l16;
          lPw[(row << 6) + (((col >> 3) ^ (row & 7)) << 3) + (col & 7)] = f2bf(e);
        }
      }

    // P·V — V fragment shared across both qh halves
    shortx8 pa[2][2];
    #pragma unroll
    for (int qh = 0; qh < 2; ++qh)
      #pragma unroll
      for (int ks = 0; ks < 2; ++ks) {
        int prow = qh*16 + l16;
        pa[qh][ks] = *(const shortx8*)(lPw + (prow << 6) + (((ks*4 + quad) ^ (prow & 7)) << 3));
      }
    #pragma unroll
    for (int ks = 0; ks < 2; ++ks)
      #pragma unroll
      for (int d = 0; d < 4; ++d) {
        shortx8 vb = *(const shortx8*)(lVt[cur] + (d*16 + l16)*64 + ks*32 + quad*8);
        acc[0][d] = __builtin_amdgcn_mfma_f32_16x16x32_bf16(pa[0][ks], vb, acc[0][d], 0, 0, 0);
        acc[1][d] = __builtin_amdgcn_mfma_f32_16x16x32_bf16(pa[1][ks], vb, acc[1][d], 0, 0, 0);
      }

    #pragma unroll
    for (int i = 0; i < 8; ++i) wc[i] = wn[i];
    __syncthreads();   // drains next-tile staging (a full compute phase old)
  }

  float rinv[2][4];
  #pragma unroll
  for (int qh = 0; qh < 2; ++qh)
    #pragma unroll
    for (int r = 0; r < 4; ++r) {
      float l = lsum[qh][r];
      #pragma unroll
      for (int o = 1; o < 16; o <<= 1) l += __shfl_xor(l, o);
      rinv[qh][r] = 1.f / l;
    }

  #pragma unroll
  for (int qh = 0; qh < 2; ++qh)
    #pragma unroll
    for (int d = 0; d < 4; ++d)
      #pragma unroll
      for (int r = 0; r < 4; ++r) {
        int q = qb + wid*32 + qh*16 + quad*4 + r;
        size_t oi = ((size_t)b*S_ + q)*DM_ + h*HD_ + d*16 + l16;
        float v = acc[qh][d][r] * rinv[qh][r];
        if (obf) ((unsigned short*)outv)[oi] = f2bf(v);
        else     ((float*)outv)[oi]          = v;
      }
}

extern "C" void kernel_launch(void* const* d_in, const int* in_sizes, int n_in,
                              void* d_out, int out_size, void* d_ws, size_t ws_size,
                              hipStream_t stream) {
  (void)in_sizes; (void)n_in; (void)out_size; (void)ws_size;
  const void* X    = d_in[0];
  const void* W    = d_in[1];
  const void* mask = d_in[2];
  const size_t SEG = (size_t)2*NH_*S_*HD_*2;  // 8.39 MB per tensor
  unsigned short* Qg = (unsigned short*)((char*)d_ws + 256);
  unsigned short* Kg = (unsigned short*)((char*)d_ws + 256 + SEG);
  unsigned short* Vt = (unsigned short*)((char*)d_ws + 256 + 2*SEG);
  unsigned long long* pk = (unsigned long long*)((char*)d_ws + 256 + 3*SEG);  // 16.8 MB

  qkv_gemm_pack<<<dim3(32, 32), 256, 0, stream>>>(X, W, mask, Qg, Kg, Vt, pk);
  attn_kernel<<<dim3(S_/QB_, NH_, 2), 256, 0, stream>>>(Qg, Kg, Vt, pk, X, d_out);
}